// Round 3
// baseline (299.533 us; speedup 1.0000x reference)
//
#include <hip/hip_runtime.h>
#include <hip/hip_bf16.h>
#include <stdint.h>

typedef __bf16 bf16x8 __attribute__((ext_vector_type(8)));
typedef float f32x4 __attribute__((ext_vector_type(4)));
typedef unsigned short u16;

#define EPS_ 1e-6f
// sizes: T=8, N=1024, E=512 (256 static + 256 dynamic), REP=28, bs=224, FT=64

__device__ __forceinline__ void gload16(const void* g, void* l) {
  __builtin_amdgcn_global_load_lds((const __attribute__((address_space(1))) void*)g,
                                   (__attribute__((address_space(3))) void*)l,
                                   16, 0, 0);
}

__device__ __forceinline__ u16 f2bf(float v) {
  __hip_bfloat16 h = __float2bfloat16(v);
  return *reinterpret_cast<u16*>(&h);
}

// dv_inv_sqrt[t][n] = rsqrt(sum_e Gc[t,n,e] + EPS); one wave per (t,n) row.
__global__ void dv_kernel(const float* __restrict__ G, const float* __restrict__ G1,
                          float* __restrict__ dv) {
  const int row = blockIdx.x * 4 + (threadIdx.x >> 6);  // 0..8191 = t*1024+n
  const int lane = threadIdx.x & 63;
  const int t = row >> 10, n = row & 1023;
  const float4 g  = ((const float4*)(G  + (size_t)n * 256))[lane];
  const float4 g1 = ((const float4*)(G1 + ((size_t)t * 1024 + n) * 256))[lane];
  float s = g.x + g.y + g.z + g.w + g1.x + g1.y + g1.z + g1.w;
  #pragma unroll
  for (int off = 1; off < 64; off <<= 1) s += __shfl_xor(s, off);
  if (lane == 0) dv[row] = rsqrtf(s + EPS_);
}

// de stage A: dep[t][c][e] = sum over n in [c*64,(c+1)*64) of Gc[t,n,e]. grid 128.
__global__ void de_partial_kernel(const float* __restrict__ G, const float* __restrict__ G1,
                                  float* __restrict__ dep) {
  const int t = blockIdx.x >> 4;
  const int c = blockIdx.x & 15;
  const int e = threadIdx.x;  // 0..511
  const int n0 = c * 64;
  float s = 0.0f;
  if (e < 256) {
    const float* p = G + (size_t)n0 * 256 + e;
    #pragma unroll 8
    for (int n = 0; n < 64; ++n) s += p[(size_t)n * 256];
  } else {
    const float* p = G1 + ((size_t)t * 1024 + n0) * 256 + (e - 256);
    #pragma unroll 8
    for (int n = 0; n < 64; ++n) s += p[(size_t)n * 256];
  }
  dep[(size_t)blockIdx.x * 512 + e] = s;
}

// de stage B: de_inv_sqrt[t][e] = rsqrt(sum_c dep[t][c][e] + EPS). grid 8.
__global__ void de_final_kernel(const float* __restrict__ dep, float* __restrict__ de) {
  const int t = blockIdx.x;
  const int e = threadIdx.x;
  float s = 0.0f;
  #pragma unroll
  for (int c = 0; c < 16; ++c) s += dep[(size_t)(t * 16 + c) * 512 + e];
  de[t * 512 + e] = rsqrtf(s + EPS_);
}

// P[t][n][e] = bf16(Gc[t,n,e] * de_is[t,e] * dv_is[t,n])   (L = P P^T, symmetric)
__global__ void pack_kernel(const float* __restrict__ G, const float* __restrict__ G1,
                            const float* __restrict__ dv, const float* __restrict__ de,
                            u16* __restrict__ P) {
  const int idx = blockIdx.x * 256 + threadIdx.x;  // over t(3b) n(10b) e4(7b)
  const int e4 = idx & 127;
  const int n  = (idx >> 7) & 1023;
  const int t  = idx >> 17;
  const int e  = e4 * 4;
  float4 g;
  if (e < 256) g = *(const float4*)(G + (size_t)n * 256 + e);
  else         g = *(const float4*)(G1 + ((size_t)t * 1024 + n) * 256 + (e - 256));
  const float4 d = *(const float4*)(de + t * 512 + e);
  const float dvn = dv[t * 1024 + n];
  u16 o[4];
  o[0] = f2bf(g.x * d.x * dvn);
  o[1] = f2bf(g.y * d.y * dvn);
  o[2] = f2bf(g.z * d.z * dvn);
  o[3] = f2bf(g.w * d.w * dvn);
  *(ushort4*)(P + ((size_t)t * 1024 + n) * 512 + e) = *(ushort4*)o;
}

// XWT[t][j=(b*64+f)][m] = bf16(xw^T). Block = 256 threads / 128 rows.
// x staged via LDS (row stride 65 -> (row+k)%32 banks, 2-way = free).
// f split by wave-half (h = tid>>7) so W access stays wave-uniform (s_load),
// acc[32] keeps VGPR ~56 (no spill, no global re-read).
__global__ __launch_bounds__(256) void xwt_kernel(const float* __restrict__ x, const float* __restrict__ w,
                           const float* __restrict__ bias, u16* __restrict__ xwt) {
  __shared__ float xs[128 * 65];
  const int tid = threadIdx.x;
  const int r0 = blockIdx.x * 128;  // first global row of block (grid 1792)
  #pragma unroll
  for (int i = 0; i < 8; ++i) {
    const int fi = tid + i * 256;           // float4 index: address is linear in fi
    const int row = fi >> 4, c4 = fi & 15;
    const float4 v = ((const float4*)(x + (size_t)r0 * 64))[fi];
    float* d = &xs[row * 65 + c4 * 4];
    d[0] = v.x; d[1] = v.y; d[2] = v.z; d[3] = v.w;
  }
  __syncthreads();
  const int row = tid & 127;
  const int h = tid >> 7;                   // wave-uniform f-half
  const int r = r0 + row;
  const int t = r / 28672;
  const int rem = r - t * 28672;
  const int b = rem >> 10;
  const int m = rem & 1023;
  float acc[32];
  #pragma unroll
  for (int f = 0; f < 32; ++f) acc[f] = bias[h * 32 + f];
  const float* wp = w + h * 32;
  #pragma unroll
  for (int k = 0; k < 64; ++k) {
    const float xk = xs[row * 65 + k];
    #pragma unroll
    for (int f = 0; f < 32; ++f) acc[f] = fmaf(xk, wp[k * 64 + f], acc[f]);
  }
  u16* o = xwt + ((size_t)t * 1792 + b * 64 + h * 32) * 1024 + m;
  #pragma unroll
  for (int f = 0; f < 32; ++f) o[(size_t)f << 10] = f2bf(acc[f]);
}

// 128x128-tile bf16 MFMA GEMM, A [M][K] row-major, B^T [N][K] row-major (m97 structure).
// MODE 0: L[t] = P[t] P[t]^T, K=512, bf16 out.   grid (64, 8)
// MODE 1: out[t][n][j] = sum_m L[t][n][m] XWT[t][j][m], K=1024, fp32 out scattered
//         to [(t*28+b)*1024+n]*64+f with j=b*64+f.   grid (112, 8)
template <int K, int MODE>
__global__ __launch_bounds__(256) void gemm_bt_kernel(
    const u16* __restrict__ Abase, const u16* __restrict__ Bbase,
    u16* __restrict__ Lw, float* __restrict__ Oo) {
  const int t = blockIdx.y;
  const int bx = blockIdx.x;
  const int row0 = (bx & 7) * 128;
  const int col0 = (bx >> 3) * 128;
  const size_t aoff = (MODE == 0) ? (size_t)t * 1024 * 512 : (size_t)t * 1024 * 1024;
  const size_t boff = (MODE == 0) ? (size_t)t * 1024 * 512 : (size_t)t * 1792 * 1024;
  const u16* A = Abase + aoff;
  const u16* B = Bbase + boff;

  __shared__ u16 As[128 * 32];
  __shared__ u16 Bs[128 * 32];

  const int tid = threadIdx.x;
  const int lane = tid & 63;
  const int wave = tid >> 6;
  const int wr = wave & 1, wc = wave >> 1;

  const int srow = tid >> 2;         // 0..63
  const int scol = (tid & 3) * 8;    // k-element offset (x8 bf16 = 16B)

  f32x4 acc[4][4] = {};

  const int l16 = lane & 15;
  const int lk = (lane >> 4) * 8;

  for (int kt = 0; kt < K / 32; ++kt) {
    const int kk = kt * 32 + scol;
    gload16(A + (size_t)(row0 + srow) * K + kk,       &As[srow * 32 + scol]);
    gload16(A + (size_t)(row0 + srow + 64) * K + kk,  &As[(srow + 64) * 32 + scol]);
    gload16(B + (size_t)(col0 + srow) * K + kk,       &Bs[srow * 32 + scol]);
    gload16(B + (size_t)(col0 + srow + 64) * K + kk,  &Bs[(srow + 64) * 32 + scol]);
    __syncthreads();  // waits vmcnt(0): LDS tiles ready
    bf16x8 af[4], bfr[4];
    #pragma unroll
    for (int i = 0; i < 4; ++i) {
      af[i]  = *(const bf16x8*)&As[(wr * 64 + i * 16 + l16) * 32 + lk];
      bfr[i] = *(const bf16x8*)&Bs[(wc * 64 + i * 16 + l16) * 32 + lk];
    }
    #pragma unroll
    for (int i = 0; i < 4; ++i)
      #pragma unroll
      for (int j = 0; j < 4; ++j)
        acc[i][j] = __builtin_amdgcn_mfma_f32_16x16x32_bf16(af[i], bfr[j], acc[i][j], 0, 0, 0);
    __syncthreads();  // protect LDS before next stage
  }

  const int l4 = lane >> 4;
  if constexpr (MODE == 0) {
    u16* Lt = Lw + (size_t)t * 1024 * 1024;
    #pragma unroll
    for (int i = 0; i < 4; ++i) {
      const int rbase = row0 + wr * 64 + i * 16 + l4 * 4;
      #pragma unroll
      for (int j = 0; j < 4; ++j) {
        const int col = col0 + wc * 64 + j * 16 + l16;
        #pragma unroll
        for (int r = 0; r < 4; ++r)
          Lt[(size_t)(rbase + r) * 1024 + col] = f2bf(acc[i][j][r]);
      }
    }
  } else {
    #pragma unroll
    for (int j = 0; j < 4; ++j) {
      const int jg = col0 + wc * 64 + j * 16 + l16;  // 0..1791
      float* Ot = Oo + (((size_t)t * 28 + (jg >> 6)) * 1024) * 64 + (jg & 63);
      #pragma unroll
      for (int i = 0; i < 4; ++i) {
        const int rbase = row0 + wr * 64 + i * 16 + l4 * 4;
        #pragma unroll
        for (int r = 0; r < 4; ++r)
          Ot[(size_t)(rbase + r) * 64] = acc[i][j][r];
      }
    }
  }
}

extern "C" void kernel_launch(void* const* d_in, const int* in_sizes, int n_in,
                              void* d_out, int out_size, void* d_ws, size_t ws_size,
                              hipStream_t stream) {
  const float* x  = (const float*)d_in[0];   // [224,1024,64]
  const float* G  = (const float*)d_in[1];   // [1024,256]
  const float* G1 = (const float*)d_in[2];   // [8,1024,256]
  const float* W  = (const float*)d_in[3];   // [64,64]
  const float* Bi = (const float*)d_in[4];   // [64]
  float* out = (float*)d_out;                // [224,1024,64] fp32

  // workspace layout (bytes): total 54,575,104
  char* ws = (char*)d_ws;
  float* dv = (float*)ws;                                  //  32 KB  [8][1024]
  float* de = (float*)(ws + 32768);                        //  16 KB  [8][512]
  u16*   P  = (u16*)(ws + 49152);                          //   8 MB  [8][1024][512]
  u16*   L  = (u16*)(ws + 49152 + 8388608);                //  16 MB  [8][1024][1024]
  u16*   XT = (u16*)(ws + 49152 + 8388608 + 16777216);     //  28 MB  [8][1792][1024]
  float* dep = (float*)L;  // 256 KB de-partials; L region is free until gemm MODE0

  dv_kernel<<<2048, 256, 0, stream>>>(G, G1, dv);
  de_partial_kernel<<<128, 512, 0, stream>>>(G, G1, dep);
  de_final_kernel<<<8, 512, 0, stream>>>(dep, de);
  pack_kernel<<<4096, 256, 0, stream>>>(G, G1, dv, de, P);
  gemm_bt_kernel<512, 0><<<dim3(64, 8), 256, 0, stream>>>(P, P, L, nullptr);
  xwt_kernel<<<1792, 256, 0, stream>>>(x, W, Bi, XT);
  gemm_bt_kernel<1024, 1><<<dim3(112, 8), 256, 0, stream>>>(L, XT, nullptr, out);
}

// Round 7
// 197.833 us; speedup vs baseline: 1.5141x; 1.5141x over previous
//
#include <hip/hip_runtime.h>
#include <hip/hip_bf16.h>
#include <stdint.h>

typedef __bf16 bf16x8 __attribute__((ext_vector_type(8)));
typedef float f32x4 __attribute__((ext_vector_type(4)));
typedef unsigned short u16;

#define EPS_ 1e-6f
// sizes: T=8, N=1024, E=512 (256 static + 256 dynamic), REP=28, bs=224, FT=64

__device__ __forceinline__ void gload16(const void* g, void* l) {
  __builtin_amdgcn_global_load_lds((const __attribute__((address_space(1))) void*)g,
                                   (__attribute__((address_space(3))) void*)l,
                                   16, 0, 0);
}

__device__ __forceinline__ u16 f2bf(float v) {
  __hip_bfloat16 h = __float2bfloat16(v);
  return *reinterpret_cast<u16*>(&h);
}

// dv_inv_sqrt[t][n] = rsqrt(sum_e Gc[t,n,e] + EPS); one wave per (t,n) row.
__global__ void dv_kernel(const float* __restrict__ G, const float* __restrict__ G1,
                          float* __restrict__ dv) {
  const int row = blockIdx.x * 4 + (threadIdx.x >> 6);  // 0..8191 = t*1024+n
  const int lane = threadIdx.x & 63;
  const int t = row >> 10, n = row & 1023;
  const float4 g  = ((const float4*)(G  + (size_t)n * 256))[lane];
  const float4 g1 = ((const float4*)(G1 + ((size_t)t * 1024 + n) * 256))[lane];
  float s = g.x + g.y + g.z + g.w + g1.x + g1.y + g1.z + g1.w;
  #pragma unroll
  for (int off = 1; off < 64; off <<= 1) s += __shfl_xor(s, off);
  if (lane == 0) dv[row] = rsqrtf(s + EPS_);
}

// de stage A: dep[t][c][e] = sum over n in [c*64,(c+1)*64) of Gc[t,n,e]. grid 128.
__global__ void de_partial_kernel(const float* __restrict__ G, const float* __restrict__ G1,
                                  float* __restrict__ dep) {
  const int t = blockIdx.x >> 4;
  const int c = blockIdx.x & 15;
  const int e = threadIdx.x;  // 0..511
  const int n0 = c * 64;
  float s = 0.0f;
  if (e < 256) {
    const float* p = G + (size_t)n0 * 256 + e;
    #pragma unroll 8
    for (int n = 0; n < 64; ++n) s += p[(size_t)n * 256];
  } else {
    const float* p = G1 + ((size_t)t * 1024 + n0) * 256 + (e - 256);
    #pragma unroll 8
    for (int n = 0; n < 64; ++n) s += p[(size_t)n * 256];
  }
  dep[(size_t)blockIdx.x * 512 + e] = s;
}

// de stage B: de_inv_sqrt[t][e] = rsqrt(sum_c dep[t][c][e] + EPS). grid 8.
__global__ void de_final_kernel(const float* __restrict__ dep, float* __restrict__ de) {
  const int t = blockIdx.x;
  const int e = threadIdx.x;
  float s = 0.0f;
  #pragma unroll
  for (int c = 0; c < 16; ++c) s += dep[(size_t)(t * 16 + c) * 512 + e];
  de[t * 512 + e] = rsqrtf(s + EPS_);
}

// P[t][n][e] = bf16(Gc[t,n,e] * de_is[t,e] * dv_is[t,n])   (L = P P^T, symmetric)
__global__ void pack_kernel(const float* __restrict__ G, const float* __restrict__ G1,
                            const float* __restrict__ dv, const float* __restrict__ de,
                            u16* __restrict__ P) {
  const int idx = blockIdx.x * 256 + threadIdx.x;  // over t(3b) n(10b) e4(7b)
  const int e4 = idx & 127;
  const int n  = (idx >> 7) & 1023;
  const int t  = idx >> 17;
  const int e  = e4 * 4;
  float4 g;
  if (e < 256) g = *(const float4*)(G + (size_t)n * 256 + e);
  else         g = *(const float4*)(G1 + ((size_t)t * 1024 + n) * 256 + (e - 256));
  const float4 d = *(const float4*)(de + t * 512 + e);
  const float dvn = dv[t * 1024 + n];
  u16 o[4];
  o[0] = f2bf(g.x * d.x * dvn);
  o[1] = f2bf(g.y * d.y * dvn);
  o[2] = f2bf(g.z * d.z * dvn);
  o[3] = f2bf(g.w * d.w * dvn);
  *(ushort4*)(P + ((size_t)t * 1024 + n) * 512 + e) = *(ushort4*)o;
}

// XWT via MFMA: per block, C-tile = 256 rows (m) x 64 f, K=64 entirely in LDS.
// W split as W_hi + W_lo (both bf16) -> only new rounding is x->bf16.
// C[r][f] = bias[f] + sum_k x[r][k]*(W_hi+W_lo)[k][f]; stored transposed to
// XT[t][(b*64+f)][m] as bf16.  grid 896 = 224 (t,b) x 4 m-blocks.
__global__ __launch_bounds__(256) void xwt_mfma_kernel(
    const float* __restrict__ x, const float* __restrict__ w,
    const float* __restrict__ bias, u16* __restrict__ xt) {
  __shared__ u16 As[256 * 72];   // x-tile bf16, row stride 72 (2-way banks)
  __shared__ u16 WT[64 * 136];   // W^T: [f][k] hi at k<64, lo at 64+k; stride 136
  const int tid = threadIdx.x;
  const int tb = blockIdx.x >> 2;          // 0..223 = t*28+b
  const int m0 = (blockIdx.x & 3) * 256;
  const size_t r0 = (size_t)tb * 1024 + m0;

  // stage W -> WT (hi/lo). lanes: f consecutive -> coalesced global reads.
  {
    const int f = tid & 63, kq = tid >> 6;
    #pragma unroll
    for (int kk = 0; kk < 16; ++kk) {
      const int k = kq * 16 + kk;
      const float wv = w[k * 64 + f];
      const float hf = __bfloat162float(__float2bfloat16(wv));
      WT[f * 136 + k]      = f2bf(wv);
      WT[f * 136 + 64 + k] = f2bf(wv - hf);
    }
  }
  // stage x-tile (256 rows x 64 k fp32 -> bf16). coalesced 1KB/instr loads.
  {
    const float4* xb = (const float4*)(x + r0 * 64);
    #pragma unroll
    for (int i = 0; i < 16; ++i) {
      const int fi = tid + i * 256;
      const int row = fi >> 4, c4 = fi & 15;
      const float4 v = xb[fi];
      ushort4 o = { f2bf(v.x), f2bf(v.y), f2bf(v.z), f2bf(v.w) };
      *(ushort4*)&As[row * 72 + c4 * 4] = o;
    }
  }
  __syncthreads();

  const int lane = tid & 63, wv_ = tid >> 6;
  const int c = lane & 15, q = lane >> 4;

  bf16x8 a[4][2], bf_[4][4];
  #pragma unroll
  for (int i = 0; i < 4; ++i)
    #pragma unroll
    for (int s = 0; s < 2; ++s)
      a[i][s] = *(const bf16x8*)&As[(wv_ * 64 + i * 16 + c) * 72 + s * 32 + q * 8];
  #pragma unroll
  for (int j = 0; j < 4; ++j)
    #pragma unroll
    for (int s = 0; s < 4; ++s)
      bf_[j][s] = *(const bf16x8*)&WT[(j * 16 + c) * 136 + s * 32 + q * 8];

  f32x4 acc[4][4];
  #pragma unroll
  for (int j = 0; j < 4; ++j) {
    const float bv = bias[j * 16 + c];
    #pragma unroll
    for (int i = 0; i < 4; ++i) acc[i][j] = { bv, bv, bv, bv };
  }
  #pragma unroll
  for (int i = 0; i < 4; ++i)
    #pragma unroll
    for (int j = 0; j < 4; ++j) {
      acc[i][j] = __builtin_amdgcn_mfma_f32_16x16x32_bf16(a[i][0], bf_[j][0], acc[i][j], 0, 0, 0);
      acc[i][j] = __builtin_amdgcn_mfma_f32_16x16x32_bf16(a[i][1], bf_[j][1], acc[i][j], 0, 0, 0);
      acc[i][j] = __builtin_amdgcn_mfma_f32_16x16x32_bf16(a[i][0], bf_[j][2], acc[i][j], 0, 0, 0);
      acc[i][j] = __builtin_amdgcn_mfma_f32_16x16x32_bf16(a[i][1], bf_[j][3], acc[i][j], 0, 0, 0);
    }

  u16* xtb = xt + (size_t)tb * 64 * 1024 + m0;   // row j=(b*64+f) base for this (t,b)
  #pragma unroll
  for (int j = 0; j < 4; ++j) {
    const int f = j * 16 + c;
    #pragma unroll
    for (int i = 0; i < 4; ++i) {
      const int mr = wv_ * 64 + i * 16 + q * 4;
      ushort4 o = { f2bf(acc[i][j][0]), f2bf(acc[i][j][1]),
                    f2bf(acc[i][j][2]), f2bf(acc[i][j][3]) };
      *(ushort4*)&xtb[(size_t)f * 1024 + mr] = o;
    }
  }
}

// 128x128-tile bf16 MFMA GEMM, A [M][K] row-major, B^T [N][K] row-major (m97 structure).
// 1D grid with bijective XCD swizzle: dispatch i -> wg (i%8)*CHUNK + i/8, so each
// XCD owns one t's panels (L2 locality). CHUNK = wgs per t.
// MODE 0: L[t] = P[t] P[t]^T, K=512, bf16 out.   grid 512, CHUNK=64
// MODE 1: out[t][n][j] = sum_m L[t][n][m] XWT[t][j][m], K=1024, fp32 out scattered.
//         grid 896, CHUNK=112
template <int K, int MODE, int CHUNK>
__global__ __launch_bounds__(256) void gemm_bt_kernel(
    const u16* __restrict__ Abase, const u16* __restrict__ Bbase,
    u16* __restrict__ Lw, float* __restrict__ Oo) {
  const int wg = (blockIdx.x & 7) * CHUNK + (blockIdx.x >> 3);
  const int t = wg / CHUNK;
  const int bx = wg - t * CHUNK;
  const int row0 = (bx & 7) * 128;
  const int col0 = (bx >> 3) * 128;
  const size_t aoff = (MODE == 0) ? (size_t)t * 1024 * 512 : (size_t)t * 1024 * 1024;
  const size_t boff = (MODE == 0) ? (size_t)t * 1024 * 512 : (size_t)t * 1792 * 1024;
  const u16* A = Abase + aoff;
  const u16* B = Bbase + boff;

  __shared__ u16 As[128 * 32];
  __shared__ u16 Bs[128 * 32];

  const int tid = threadIdx.x;
  const int lane = tid & 63;
  const int wave = tid >> 6;
  const int wr = wave & 1, wc = wave >> 1;

  const int srow = tid >> 2;         // 0..63
  const int scol = (tid & 3) * 8;    // k-element offset (x8 bf16 = 16B)

  f32x4 acc[4][4] = {};

  const int l16 = lane & 15;
  const int lk = (lane >> 4) * 8;

  for (int kt = 0; kt < K / 32; ++kt) {
    const int kk = kt * 32 + scol;
    gload16(A + (size_t)(row0 + srow) * K + kk,       &As[srow * 32 + scol]);
    gload16(A + (size_t)(row0 + srow + 64) * K + kk,  &As[(srow + 64) * 32 + scol]);
    gload16(B + (size_t)(col0 + srow) * K + kk,       &Bs[srow * 32 + scol]);
    gload16(B + (size_t)(col0 + srow + 64) * K + kk,  &Bs[(srow + 64) * 32 + scol]);
    __syncthreads();  // waits vmcnt(0): LDS tiles ready
    bf16x8 af[4], bfr[4];
    #pragma unroll
    for (int i = 0; i < 4; ++i) {
      af[i]  = *(const bf16x8*)&As[(wr * 64 + i * 16 + l16) * 32 + lk];
      bfr[i] = *(const bf16x8*)&Bs[(wc * 64 + i * 16 + l16) * 32 + lk];
    }
    #pragma unroll
    for (int i = 0; i < 4; ++i)
      #pragma unroll
      for (int j = 0; j < 4; ++j)
        acc[i][j] = __builtin_amdgcn_mfma_f32_16x16x32_bf16(af[i], bfr[j], acc[i][j], 0, 0, 0);
    __syncthreads();  // protect LDS before next stage
  }

  const int l4 = lane >> 4;
  if constexpr (MODE == 0) {
    u16* Lt = Lw + (size_t)t * 1024 * 1024;
    #pragma unroll
    for (int i = 0; i < 4; ++i) {
      const int rbase = row0 + wr * 64 + i * 16 + l4 * 4;
      #pragma unroll
      for (int j = 0; j < 4; ++j) {
        const int col = col0 + wc * 64 + j * 16 + l16;
        #pragma unroll
        for (int r = 0; r < 4; ++r)
          Lt[(size_t)(rbase + r) * 1024 + col] = f2bf(acc[i][j][r]);
      }
    }
  } else {
    #pragma unroll
    for (int j = 0; j < 4; ++j) {
      const int jg = col0 + wc * 64 + j * 16 + l16;  // 0..1791
      float* Ot = Oo + (((size_t)t * 28 + (jg >> 6)) * 1024) * 64 + (jg & 63);
      #pragma unroll
      for (int i = 0; i < 4; ++i) {
        const int rbase = row0 + wr * 64 + i * 16 + l4 * 4;
        #pragma unroll
        for (int r = 0; r < 4; ++r)
          Ot[(size_t)(rbase + r) * 64] = acc[i][j][r];
      }
    }
  }
}

extern "C" void kernel_launch(void* const* d_in, const int* in_sizes, int n_in,
                              void* d_out, int out_size, void* d_ws, size_t ws_size,
                              hipStream_t stream) {
  const float* x  = (const float*)d_in[0];   // [224,1024,64]
  const float* G  = (const float*)d_in[1];   // [1024,256]
  const float* G1 = (const float*)d_in[2];   // [8,1024,256]
  const float* W  = (const float*)d_in[3];   // [64,64]
  const float* Bi = (const float*)d_in[4];   // [64]
  float* out = (float*)d_out;                // [224,1024,64] fp32

  // workspace layout (bytes): total 54,575,104
  char* ws = (char*)d_ws;
  float* dv = (float*)ws;                                  //  32 KB  [8][1024]
  float* de = (float*)(ws + 32768);                        //  16 KB  [8][512]
  u16*   P  = (u16*)(ws + 49152);                          //   8 MB  [8][1024][512]
  u16*   L  = (u16*)(ws + 49152 + 8388608);                //  16 MB  [8][1024][1024]
  u16*   XT = (u16*)(ws + 49152 + 8388608 + 16777216);     //  28 MB  [8][1792][1024]
  float* dep = (float*)L;  // 256 KB de-partials; L region is free until gemm MODE0

  dv_kernel<<<2048, 256, 0, stream>>>(G, G1, dv);
  de_partial_kernel<<<128, 512, 0, stream>>>(G, G1, dep);
  de_final_kernel<<<8, 512, 0, stream>>>(dep, de);
  pack_kernel<<<4096, 256, 0, stream>>>(G, G1, dv, de, P);
  gemm_bt_kernel<512, 0, 64><<<512, 256, 0, stream>>>(P, P, L, nullptr);
  xwt_mfma_kernel<<<896, 256, 0, stream>>>(x, W, Bi, XT);
  gemm_bt_kernel<1024, 1, 112><<<896, 256, 0, stream>>>(L, XT, nullptr, out);
}

// Round 11
// 189.964 us; speedup vs baseline: 1.5768x; 1.0414x over previous
//
#include <hip/hip_runtime.h>
#include <hip/hip_bf16.h>
#include <stdint.h>

typedef __bf16 bf16x8 __attribute__((ext_vector_type(8)));
typedef float f32x4 __attribute__((ext_vector_type(4)));
typedef unsigned short u16;

#define EPS_ 1e-6f
// sizes: T=8, N=1024, E=512 (256 static + 256 dynamic), REP=28, bs=224, FT=64

__device__ __forceinline__ void gload16(const void* g, void* l) {
  __builtin_amdgcn_global_load_lds((const __attribute__((address_space(1))) void*)g,
                                   (__attribute__((address_space(3))) void*)l,
                                   16, 0, 0);
}

__device__ __forceinline__ u16 f2bf(float v) {
  __hip_bfloat16 h = __float2bfloat16(v);
  return *reinterpret_cast<u16*>(&h);
}

// dv_inv_sqrt[t][n] = rsqrt(sum_e Gc[t,n,e] + EPS); one wave per (t,n) row.
__global__ void dv_kernel(const float* __restrict__ G, const float* __restrict__ G1,
                          float* __restrict__ dv) {
  const int row = blockIdx.x * 4 + (threadIdx.x >> 6);  // 0..8191 = t*1024+n
  const int lane = threadIdx.x & 63;
  const int t = row >> 10, n = row & 1023;
  const float4 g  = ((const float4*)(G  + (size_t)n * 256))[lane];
  const float4 g1 = ((const float4*)(G1 + ((size_t)t * 1024 + n) * 256))[lane];
  float s = g.x + g.y + g.z + g.w + g1.x + g1.y + g1.z + g1.w;
  #pragma unroll
  for (int off = 1; off < 64; off <<= 1) s += __shfl_xor(s, off);
  if (lane == 0) dv[row] = rsqrtf(s + EPS_);
}

// de stage A: dep[t][c][e] = sum over n in [c*64,(c+1)*64) of Gc[t,n,e]. grid 128.
__global__ void de_partial_kernel(const float* __restrict__ G, const float* __restrict__ G1,
                                  float* __restrict__ dep) {
  const int t = blockIdx.x >> 4;
  const int c = blockIdx.x & 15;
  const int e = threadIdx.x;  // 0..511
  const int n0 = c * 64;
  float s = 0.0f;
  if (e < 256) {
    const float* p = G + (size_t)n0 * 256 + e;
    #pragma unroll 8
    for (int n = 0; n < 64; ++n) s += p[(size_t)n * 256];
  } else {
    const float* p = G1 + ((size_t)t * 1024 + n0) * 256 + (e - 256);
    #pragma unroll 8
    for (int n = 0; n < 64; ++n) s += p[(size_t)n * 256];
  }
  dep[(size_t)blockIdx.x * 512 + e] = s;
}

// de stage B: de_inv_sqrt[t][e] = rsqrt(sum_c dep[t][c][e] + EPS). grid 8.
__global__ void de_final_kernel(const float* __restrict__ dep, float* __restrict__ de) {
  const int t = blockIdx.x;
  const int e = threadIdx.x;
  float s = 0.0f;
  #pragma unroll
  for (int c = 0; c < 16; ++c) s += dep[(size_t)(t * 16 + c) * 512 + e];
  de[t * 512 + e] = rsqrtf(s + EPS_);
}

// P[t][n][e] = bf16(Gc[t,n,e] * de_is[t,e] * dv_is[t,n])   (L = P P^T, symmetric)
__global__ void pack_kernel(const float* __restrict__ G, const float* __restrict__ G1,
                            const float* __restrict__ dv, const float* __restrict__ de,
                            u16* __restrict__ P) {
  const int idx = blockIdx.x * 256 + threadIdx.x;  // over t(3b) n(10b) e4(7b)
  const int e4 = idx & 127;
  const int n  = (idx >> 7) & 1023;
  const int t  = idx >> 17;
  const int e  = e4 * 4;
  float4 g;
  if (e < 256) g = *(const float4*)(G + (size_t)n * 256 + e);
  else         g = *(const float4*)(G1 + ((size_t)t * 1024 + n) * 256 + (e - 256));
  const float4 d = *(const float4*)(de + t * 512 + e);
  const float dvn = dv[t * 1024 + n];
  u16 o[4];
  o[0] = f2bf(g.x * d.x * dvn);
  o[1] = f2bf(g.y * d.y * dvn);
  o[2] = f2bf(g.z * d.z * dvn);
  o[3] = f2bf(g.w * d.w * dvn);
  *(ushort4*)(P + ((size_t)t * 1024 + n) * 512 + e) = *(ushort4*)o;
}

// XWT via MFMA: per block, C-tile = 256 rows (m) x 64 f, K=64 entirely in LDS.
// W split as W_hi + W_lo (both bf16) -> only new rounding is x->bf16.
__global__ __launch_bounds__(256) void xwt_mfma_kernel(
    const float* __restrict__ x, const float* __restrict__ w,
    const float* __restrict__ bias, u16* __restrict__ xt) {
  __shared__ u16 As[256 * 72];   // x-tile bf16, row stride 72 (2-way banks)
  __shared__ u16 WT[64 * 136];   // W^T: [f][k] hi at k<64, lo at 64+k; stride 136
  const int tid = threadIdx.x;
  const int tb = blockIdx.x >> 2;          // 0..223 = t*28+b
  const int m0 = (blockIdx.x & 3) * 256;
  const size_t r0 = (size_t)tb * 1024 + m0;

  {
    const int f = tid & 63, kq = tid >> 6;
    #pragma unroll
    for (int kk = 0; kk < 16; ++kk) {
      const int k = kq * 16 + kk;
      const float wv = w[k * 64 + f];
      const float hf = __bfloat162float(__float2bfloat16(wv));
      WT[f * 136 + k]      = f2bf(wv);
      WT[f * 136 + 64 + k] = f2bf(wv - hf);
    }
  }
  {
    const float4* xb = (const float4*)(x + r0 * 64);
    #pragma unroll
    for (int i = 0; i < 16; ++i) {
      const int fi = tid + i * 256;
      const int row = fi >> 4, c4 = fi & 15;
      const float4 v = xb[fi];
      ushort4 o = { f2bf(v.x), f2bf(v.y), f2bf(v.z), f2bf(v.w) };
      *(ushort4*)&As[row * 72 + c4 * 4] = o;
    }
  }
  __syncthreads();

  const int lane = tid & 63, wv_ = tid >> 6;
  const int c = lane & 15, q = lane >> 4;

  bf16x8 a[4][2], bf_[4][4];
  #pragma unroll
  for (int i = 0; i < 4; ++i)
    #pragma unroll
    for (int s = 0; s < 2; ++s)
      a[i][s] = *(const bf16x8*)&As[(wv_ * 64 + i * 16 + c) * 72 + s * 32 + q * 8];
  #pragma unroll
  for (int j = 0; j < 4; ++j)
    #pragma unroll
    for (int s = 0; s < 4; ++s)
      bf_[j][s] = *(const bf16x8*)&WT[(j * 16 + c) * 136 + s * 32 + q * 8];

  f32x4 acc[4][4];
  #pragma unroll
  for (int j = 0; j < 4; ++j) {
    const float bv = bias[j * 16 + c];
    #pragma unroll
    for (int i = 0; i < 4; ++i) acc[i][j] = { bv, bv, bv, bv };
  }
  #pragma unroll
  for (int i = 0; i < 4; ++i)
    #pragma unroll
    for (int j = 0; j < 4; ++j) {
      acc[i][j] = __builtin_amdgcn_mfma_f32_16x16x32_bf16(a[i][0], bf_[j][0], acc[i][j], 0, 0, 0);
      acc[i][j] = __builtin_amdgcn_mfma_f32_16x16x32_bf16(a[i][1], bf_[j][1], acc[i][j], 0, 0, 0);
      acc[i][j] = __builtin_amdgcn_mfma_f32_16x16x32_bf16(a[i][0], bf_[j][2], acc[i][j], 0, 0, 0);
      acc[i][j] = __builtin_amdgcn_mfma_f32_16x16x32_bf16(a[i][1], bf_[j][3], acc[i][j], 0, 0, 0);
    }

  u16* xtb = xt + (size_t)tb * 64 * 1024 + m0;
  #pragma unroll
  for (int j = 0; j < 4; ++j) {
    const int f = j * 16 + c;
    #pragma unroll
    for (int i = 0; i < 4; ++i) {
      const int mr = wv_ * 64 + i * 16 + q * 4;
      ushort4 o = { f2bf(acc[i][j][0]), f2bf(acc[i][j][1]),
                    f2bf(acc[i][j][2]), f2bf(acc[i][j][3]) };
      *(ushort4*)&xtb[(size_t)f * 1024 + mr] = o;
    }
  }
}

// 128x128-tile bf16 MFMA GEMM, A [M][K] row-major, B^T [N][K] row-major.
// BK=64 (half the barriers of BK=32) + rule-21 XOR swizzle:
//   LDS dest stays LINEAR (global_load_lds requirement); the global SOURCE
//   16B-chunk is pre-permuted c_src = c_dst ^ (row&7); fragment reads use the
//   same involution slot = c ^ (row&7). Rows are 128B (32 banks), so 16
//   consecutive rows reading one 16B chunk land on 8 distinct bank-quads
//   -> 2-way aliasing = free (was 8-way with [128][32]).
// XCD swizzle: dispatch i -> wg (i%8)*CHUNK + i/8 (bijective; one t per XCD).
// MODE 0: L[t] = P[t] P[t]^T, K=512, bf16 out.   grid 512, CHUNK=64
// MODE 1: out[t][n][j] = sum_m L[t][n][m] XWT[t][j][m], K=1024, fp32 scattered.
//         grid 896, CHUNK=112
template <int K, int MODE, int CHUNK>
__global__ __launch_bounds__(256) void gemm_bt_kernel(
    const u16* __restrict__ Abase, const u16* __restrict__ Bbase,
    u16* __restrict__ Lw, float* __restrict__ Oo) {
  const int wg = (blockIdx.x & 7) * CHUNK + (blockIdx.x >> 3);
  const int t = wg / CHUNK;
  const int bx = wg - t * CHUNK;
  const int row0 = (bx & 7) * 128;
  const int col0 = (bx >> 3) * 128;
  const size_t aoff = (MODE == 0) ? (size_t)t * 1024 * 512 : (size_t)t * 1024 * 1024;
  const size_t boff = (MODE == 0) ? (size_t)t * 1024 * 512 : (size_t)t * 1792 * 1024;
  const u16* A = Abase + aoff;
  const u16* B = Bbase + boff;

  __shared__ u16 As[128 * 64];   // 16 KB, 128B rows
  __shared__ u16 Bs[128 * 64];   // 16 KB

  const int tid = threadIdx.x;
  const int lane = tid & 63;
  const int wave = tid >> 6;
  const int wr = wave & 1, wc = wave >> 1;

  const int srow8 = tid >> 3;     // 0..31: row within each 32-row staging group
  const int schunk = tid & 7;     // dest 16B slot within the 128B row

  f32x4 acc[4][4] = {};

  const int l16 = lane & 15;
  const int q = lane >> 4;        // 0..3

  for (int kt = 0; kt < K / 64; ++kt) {
    const int kk0 = kt * 64;
    #pragma unroll
    for (int i = 0; i < 4; ++i) {
      const int row = i * 32 + srow8;                  // tile-relative 0..127
      const int csrc = schunk ^ (row & 7);             // pre-swizzled source chunk
      // dest byte = row*128 + schunk*16 = waveBase + lane*16 (linear per wave)
      gload16(A + (size_t)(row0 + row) * K + kk0 + csrc * 8, &As[row * 64 + schunk * 8]);
      gload16(B + (size_t)(col0 + row) * K + kk0 + csrc * 8, &Bs[row * 64 + schunk * 8]);
    }
    __syncthreads();  // waits vmcnt(0): LDS tiles ready

    bf16x8 af[4][2], bfr[4][2];
    #pragma unroll
    for (int i = 0; i < 4; ++i) {
      const int ar = wr * 64 + i * 16 + l16;
      const int br = wc * 64 + i * 16 + l16;
      #pragma unroll
      for (int h = 0; h < 2; ++h) {
        const int ca = (h * 4 + q) ^ (ar & 7);         // swizzled read slot
        const int cb = (h * 4 + q) ^ (br & 7);
        af[i][h]  = *(const bf16x8*)&As[ar * 64 + ca * 8];
        bfr[i][h] = *(const bf16x8*)&Bs[br * 64 + cb * 8];
      }
    }
    #pragma unroll
    for (int i = 0; i < 4; ++i)
      #pragma unroll
      for (int j = 0; j < 4; ++j) {
        acc[i][j] = __builtin_amdgcn_mfma_f32_16x16x32_bf16(af[i][0], bfr[j][0], acc[i][j], 0, 0, 0);
        acc[i][j] = __builtin_amdgcn_mfma_f32_16x16x32_bf16(af[i][1], bfr[j][1], acc[i][j], 0, 0, 0);
      }
    __syncthreads();  // protect LDS before next stage
  }

  const int l4 = q;
  if constexpr (MODE == 0) {
    u16* Lt = Lw + (size_t)t * 1024 * 1024;
    #pragma unroll
    for (int i = 0; i < 4; ++i) {
      const int rbase = row0 + wr * 64 + i * 16 + l4 * 4;
      #pragma unroll
      for (int j = 0; j < 4; ++j) {
        const int col = col0 + wc * 64 + j * 16 + l16;
        #pragma unroll
        for (int r = 0; r < 4; ++r)
          Lt[(size_t)(rbase + r) * 1024 + col] = f2bf(acc[i][j][r]);
      }
    }
  } else {
    #pragma unroll
    for (int j = 0; j < 4; ++j) {
      const int jg = col0 + wc * 64 + j * 16 + l16;  // 0..1791
      float* Ot = Oo + (((size_t)t * 28 + (jg >> 6)) * 1024) * 64 + (jg & 63);
      #pragma unroll
      for (int i = 0; i < 4; ++i) {
        const int rbase = row0 + wr * 64 + i * 16 + l4 * 4;
        #pragma unroll
        for (int r = 0; r < 4; ++r)
          Ot[(size_t)(rbase + r) * 64] = acc[i][j][r];
      }
    }
  }
}

extern "C" void kernel_launch(void* const* d_in, const int* in_sizes, int n_in,
                              void* d_out, int out_size, void* d_ws, size_t ws_size,
                              hipStream_t stream) {
  const float* x  = (const float*)d_in[0];   // [224,1024,64]
  const float* G  = (const float*)d_in[1];   // [1024,256]
  const float* G1 = (const float*)d_in[2];   // [8,1024,256]
  const float* W  = (const float*)d_in[3];   // [64,64]
  const float* Bi = (const float*)d_in[4];   // [64]
  float* out = (float*)d_out;                // [224,1024,64] fp32

  // workspace layout (bytes): total 54,575,104
  char* ws = (char*)d_ws;
  float* dv = (float*)ws;                                  //  32 KB  [8][1024]
  float* de = (float*)(ws + 32768);                        //  16 KB  [8][512]
  u16*   P  = (u16*)(ws + 49152);                          //   8 MB  [8][1024][512]
  u16*   L  = (u16*)(ws + 49152 + 8388608);                //  16 MB  [8][1024][1024]
  u16*   XT = (u16*)(ws + 49152 + 8388608 + 16777216);     //  28 MB  [8][1792][1024]
  float* dep = (float*)L;  // 256 KB de-partials; L region is free until gemm MODE0

  dv_kernel<<<2048, 256, 0, stream>>>(G, G1, dv);
  de_partial_kernel<<<128, 512, 0, stream>>>(G, G1, dep);
  de_final_kernel<<<8, 512, 0, stream>>>(dep, de);
  pack_kernel<<<4096, 256, 0, stream>>>(G, G1, dv, de, P);
  gemm_bt_kernel<512, 0, 64><<<512, 256, 0, stream>>>(P, P, L, nullptr);
  xwt_mfma_kernel<<<896, 256, 0, stream>>>(x, W, Bi, XT);
  gemm_bt_kernel<1024, 1, 112><<<896, 256, 0, stream>>>(L, XT, nullptr, out);
}

// Round 12
// 183.813 us; speedup vs baseline: 1.6295x; 1.0335x over previous
//
#include <hip/hip_runtime.h>
#include <hip/hip_bf16.h>
#include <stdint.h>

typedef __bf16 bf16x8 __attribute__((ext_vector_type(8)));
typedef float f32x4 __attribute__((ext_vector_type(4)));
typedef unsigned short u16;

#define EPS_ 1e-6f
// sizes: T=8, N=1024, E=512 (256 static + 256 dynamic), REP=28, bs=224, FT=64

__device__ __forceinline__ void gload16(const void* g, void* l) {
  __builtin_amdgcn_global_load_lds((const __attribute__((address_space(1))) void*)g,
                                   (__attribute__((address_space(3))) void*)l,
                                   16, 0, 0);
}

__device__ __forceinline__ u16 f2bf(float v) {
  __hip_bfloat16 h = __float2bfloat16(v);
  return *reinterpret_cast<u16*>(&h);
}

// Fused degree kernel (saves 1 launch):
// blocks 0..127   : de-partials dep[t][c][e] = sum over 64-row chunk (512 thr, e=tid)
// blocks 128..1151: dv[t][n] = rsqrt(row sum + eps), one wave per row, 8 rows/block
__global__ __launch_bounds__(512) void deg_kernel(const float* __restrict__ G,
                                                  const float* __restrict__ G1,
                                                  float* __restrict__ dv,
                                                  float* __restrict__ dep) {
  const int tid = threadIdx.x;
  if (blockIdx.x < 128) {
    const int t = blockIdx.x >> 4, c = blockIdx.x & 15, e = tid, n0 = c * 64;
    float s = 0.0f;
    if (e < 256) {
      const float* p = G + (size_t)n0 * 256 + e;
      #pragma unroll 8
      for (int n = 0; n < 64; ++n) s += p[(size_t)n * 256];
    } else {
      const float* p = G1 + ((size_t)t * 1024 + n0) * 256 + (e - 256);
      #pragma unroll 8
      for (int n = 0; n < 64; ++n) s += p[(size_t)n * 256];
    }
    dep[(size_t)blockIdx.x * 512 + e] = s;
  } else {
    const int row = (blockIdx.x - 128) * 8 + (tid >> 6);  // 0..8191 = t*1024+n
    const int lane = tid & 63;
    const int t = row >> 10, n = row & 1023;
    const float4 g  = ((const float4*)(G  + (size_t)n * 256))[lane];
    const float4 g1 = ((const float4*)(G1 + ((size_t)t * 1024 + n) * 256))[lane];
    float s = g.x + g.y + g.z + g.w + g1.x + g1.y + g1.z + g1.w;
    #pragma unroll
    for (int off = 1; off < 64; off <<= 1) s += __shfl_xor(s, off);
    if (lane == 0) dv[row] = rsqrtf(s + EPS_);
  }
}

// Fused xwt + pack kernel (saves 2 launches, co-schedules independent work):
// blocks 0..895  : XWT via MFMA (identical to verified xwt_mfma body)
// blocks 896..1151: pack P[t][n][e] = bf16(Gc*de_is*dv_is); de finalized inline
//                  from dep into LDS (redundant per block; dep is L2-resident).
__global__ __launch_bounds__(256) void packxwt_kernel(
    const float* __restrict__ x, const float* __restrict__ w,
    const float* __restrict__ bias,
    const float* __restrict__ G, const float* __restrict__ G1,
    const float* __restrict__ dv, const float* __restrict__ dep,
    u16* __restrict__ xt, u16* __restrict__ P) {
  __shared__ u16 smem[256 * 72 + 64 * 136];  // xwt: As+WT; pack: de_s (512 f32)
  const int tid = threadIdx.x;

  if (blockIdx.x < 896) {
    // ---------------- XWT branch (verified body; As/WT alias smem) ----------
    u16* As = smem;                 // [256][72]
    u16* WT = smem + 256 * 72;      // [64][136]
    const int tb = blockIdx.x >> 2;          // 0..223 = t*28+b
    const int m0 = (blockIdx.x & 3) * 256;
    const size_t r0 = (size_t)tb * 1024 + m0;

    {
      const int f = tid & 63, kq = tid >> 6;
      #pragma unroll
      for (int kk = 0; kk < 16; ++kk) {
        const int k = kq * 16 + kk;
        const float wv = w[k * 64 + f];
        const float hf = __bfloat162float(__float2bfloat16(wv));
        WT[f * 136 + k]      = f2bf(wv);
        WT[f * 136 + 64 + k] = f2bf(wv - hf);
      }
    }
    {
      const float4* xb = (const float4*)(x + r0 * 64);
      #pragma unroll
      for (int i = 0; i < 16; ++i) {
        const int fi = tid + i * 256;
        const int row = fi >> 4, c4 = fi & 15;
        const float4 v = xb[fi];
        ushort4 o = { f2bf(v.x), f2bf(v.y), f2bf(v.z), f2bf(v.w) };
        *(ushort4*)&As[row * 72 + c4 * 4] = o;
      }
    }
    __syncthreads();

    const int lane = tid & 63, wv_ = tid >> 6;
    const int c = lane & 15, q = lane >> 4;

    bf16x8 a[4][2], bf_[4][4];
    #pragma unroll
    for (int i = 0; i < 4; ++i)
      #pragma unroll
      for (int s = 0; s < 2; ++s)
        a[i][s] = *(const bf16x8*)&As[(wv_ * 64 + i * 16 + c) * 72 + s * 32 + q * 8];
    #pragma unroll
    for (int j = 0; j < 4; ++j)
      #pragma unroll
      for (int s = 0; s < 4; ++s)
        bf_[j][s] = *(const bf16x8*)&WT[(j * 16 + c) * 136 + s * 32 + q * 8];

    f32x4 acc[4][4];
    #pragma unroll
    for (int j = 0; j < 4; ++j) {
      const float bv = bias[j * 16 + c];
      #pragma unroll
      for (int i = 0; i < 4; ++i) acc[i][j] = { bv, bv, bv, bv };
    }
    #pragma unroll
    for (int i = 0; i < 4; ++i)
      #pragma unroll
      for (int j = 0; j < 4; ++j) {
        acc[i][j] = __builtin_amdgcn_mfma_f32_16x16x32_bf16(a[i][0], bf_[j][0], acc[i][j], 0, 0, 0);
        acc[i][j] = __builtin_amdgcn_mfma_f32_16x16x32_bf16(a[i][1], bf_[j][1], acc[i][j], 0, 0, 0);
        acc[i][j] = __builtin_amdgcn_mfma_f32_16x16x32_bf16(a[i][0], bf_[j][2], acc[i][j], 0, 0, 0);
        acc[i][j] = __builtin_amdgcn_mfma_f32_16x16x32_bf16(a[i][1], bf_[j][3], acc[i][j], 0, 0, 0);
      }

    u16* xtb = xt + (size_t)tb * 64 * 1024 + m0;
    #pragma unroll
    for (int j = 0; j < 4; ++j) {
      const int f = j * 16 + c;
      #pragma unroll
      for (int i = 0; i < 4; ++i) {
        const int mr = wv_ * 64 + i * 16 + q * 4;
        ushort4 o = { f2bf(acc[i][j][0]), f2bf(acc[i][j][1]),
                      f2bf(acc[i][j][2]), f2bf(acc[i][j][3]) };
        *(ushort4*)&xtb[(size_t)f * 1024 + mr] = o;
      }
    }
  } else {
    // ---------------- pack branch -----------------------------------------
    float* de_s = (float*)smem;              // 512 f32
    const int pb = blockIdx.x - 896;         // 0..255
    const int t = pb >> 5;
    const int n0 = (pb & 31) * 32;
    for (int e = tid; e < 512; e += 256) {
      float s = 0.0f;
      #pragma unroll
      for (int c = 0; c < 16; ++c) s += dep[(size_t)(t * 16 + c) * 512 + e];
      de_s[e] = rsqrtf(s + EPS_);
    }
    __syncthreads();
    const int e = (tid & 127) * 4;
    const int rsub = tid >> 7;               // 0..1
    #pragma unroll
    for (int it = 0; it < 16; ++it) {
      const int n = n0 + it * 2 + rsub;
      float4 g;
      if (e < 256) g = *(const float4*)(G + (size_t)n * 256 + e);
      else         g = *(const float4*)(G1 + ((size_t)t * 1024 + n) * 256 + (e - 256));
      const float dvn = dv[t * 1024 + n];    // wave-uniform -> s_load
      u16 o[4];
      o[0] = f2bf(g.x * de_s[e]     * dvn);
      o[1] = f2bf(g.y * de_s[e + 1] * dvn);
      o[2] = f2bf(g.z * de_s[e + 2] * dvn);
      o[3] = f2bf(g.w * de_s[e + 3] * dvn);
      *(ushort4*)(P + ((size_t)t * 1024 + n) * 512 + e) = *(ushort4*)o;
    }
  }
}

// 128x128-tile bf16 MFMA GEMM, A [M][K] row-major, B^T [N][K] row-major.
// BK=64 + rule-21 XOR swizzle (verified R11: bank conflicts 3.67M -> 0).
// XCD swizzle: dispatch i -> wg (i%8)*CHUNK + i/8 (bijective; one t per XCD).
// MODE 0: L[t] = P[t] P[t]^T, K=512, bf16 out.   grid 512, CHUNK=64
// MODE 1: out[t][n][j] = sum_m L[t][n][m] XWT[t][j][m], K=1024, fp32 scattered.
//         grid 896, CHUNK=112
template <int K, int MODE, int CHUNK>
__global__ __launch_bounds__(256) void gemm_bt_kernel(
    const u16* __restrict__ Abase, const u16* __restrict__ Bbase,
    u16* __restrict__ Lw, float* __restrict__ Oo) {
  const int wg = (blockIdx.x & 7) * CHUNK + (blockIdx.x >> 3);
  const int t = wg / CHUNK;
  const int bx = wg - t * CHUNK;
  const int row0 = (bx & 7) * 128;
  const int col0 = (bx >> 3) * 128;
  const size_t aoff = (MODE == 0) ? (size_t)t * 1024 * 512 : (size_t)t * 1024 * 1024;
  const size_t boff = (MODE == 0) ? (size_t)t * 1024 * 512 : (size_t)t * 1792 * 1024;
  const u16* A = Abase + aoff;
  const u16* B = Bbase + boff;

  __shared__ u16 As[128 * 64];   // 16 KB, 128B rows
  __shared__ u16 Bs[128 * 64];   // 16 KB

  const int tid = threadIdx.x;
  const int lane = tid & 63;
  const int wave = tid >> 6;
  const int wr = wave & 1, wc = wave >> 1;

  const int srow8 = tid >> 3;     // 0..31: row within each 32-row staging group
  const int schunk = tid & 7;     // dest 16B slot within the 128B row

  f32x4 acc[4][4] = {};

  const int l16 = lane & 15;
  const int q = lane >> 4;        // 0..3

  for (int kt = 0; kt < K / 64; ++kt) {
    const int kk0 = kt * 64;
    #pragma unroll
    for (int i = 0; i < 4; ++i) {
      const int row = i * 32 + srow8;                  // tile-relative 0..127
      const int csrc = schunk ^ (row & 7);             // pre-swizzled source chunk
      gload16(A + (size_t)(row0 + row) * K + kk0 + csrc * 8, &As[row * 64 + schunk * 8]);
      gload16(B + (size_t)(col0 + row) * K + kk0 + csrc * 8, &Bs[row * 64 + schunk * 8]);
    }
    __syncthreads();  // waits vmcnt(0): LDS tiles ready

    bf16x8 af[4][2], bfr[4][2];
    #pragma unroll
    for (int i = 0; i < 4; ++i) {
      const int ar = wr * 64 + i * 16 + l16;
      const int br = wc * 64 + i * 16 + l16;
      #pragma unroll
      for (int h = 0; h < 2; ++h) {
        const int ca = (h * 4 + q) ^ (ar & 7);         // swizzled read slot
        const int cb = (h * 4 + q) ^ (br & 7);
        af[i][h]  = *(const bf16x8*)&As[ar * 64 + ca * 8];
        bfr[i][h] = *(const bf16x8*)&Bs[br * 64 + cb * 8];
      }
    }
    #pragma unroll
    for (int i = 0; i < 4; ++i)
      #pragma unroll
      for (int j = 0; j < 4; ++j) {
        acc[i][j] = __builtin_amdgcn_mfma_f32_16x16x32_bf16(af[i][0], bfr[j][0], acc[i][j], 0, 0, 0);
        acc[i][j] = __builtin_amdgcn_mfma_f32_16x16x32_bf16(af[i][1], bfr[j][1], acc[i][j], 0, 0, 0);
      }
    __syncthreads();  // protect LDS before next stage
  }

  const int l4 = q;
  if constexpr (MODE == 0) {
    u16* Lt = Lw + (size_t)t * 1024 * 1024;
    #pragma unroll
    for (int i = 0; i < 4; ++i) {
      const int rbase = row0 + wr * 64 + i * 16 + l4 * 4;
      #pragma unroll
      for (int j = 0; j < 4; ++j) {
        const int col = col0 + wc * 64 + j * 16 + l16;
        #pragma unroll
        for (int r = 0; r < 4; ++r)
          Lt[(size_t)(rbase + r) * 1024 + col] = f2bf(acc[i][j][r]);
      }
    }
  } else {
    #pragma unroll
    for (int j = 0; j < 4; ++j) {
      const int jg = col0 + wc * 64 + j * 16 + l16;  // 0..1791
      float* Ot = Oo + (((size_t)t * 28 + (jg >> 6)) * 1024) * 64 + (jg & 63);
      #pragma unroll
      for (int i = 0; i < 4; ++i) {
        const int rbase = row0 + wr * 64 + i * 16 + l4 * 4;
        #pragma unroll
        for (int r = 0; r < 4; ++r)
          Ot[(size_t)(rbase + r) * 64] = acc[i][j][r];
      }
    }
  }
}

extern "C" void kernel_launch(void* const* d_in, const int* in_sizes, int n_in,
                              void* d_out, int out_size, void* d_ws, size_t ws_size,
                              hipStream_t stream) {
  const float* x  = (const float*)d_in[0];   // [224,1024,64]
  const float* G  = (const float*)d_in[1];   // [1024,256]
  const float* G1 = (const float*)d_in[2];   // [8,1024,256]
  const float* W  = (const float*)d_in[3];   // [64,64]
  const float* Bi = (const float*)d_in[4];   // [64]
  float* out = (float*)d_out;                // [224,1024,64] fp32

  // workspace layout (bytes): total 54,575,104
  char* ws = (char*)d_ws;
  float* dv = (float*)ws;                                  //  32 KB  [8][1024]
  u16*   P  = (u16*)(ws + 49152);                          //   8 MB  [8][1024][512]
  u16*   L  = (u16*)(ws + 49152 + 8388608);                //  16 MB  [8][1024][1024]
  u16*   XT = (u16*)(ws + 49152 + 8388608 + 16777216);     //  28 MB  [8][1792][1024]
  float* dep = (float*)L;  // 256 KB de-partials; L region is free until gemm MODE0

  deg_kernel<<<1152, 512, 0, stream>>>(G, G1, dv, dep);
  packxwt_kernel<<<1152, 256, 0, stream>>>(x, W, Bi, G, G1, dv, dep, XT, P);
  gemm_bt_kernel<512, 0, 64><<<512, 256, 0, stream>>>(P, P, L, nullptr);
  gemm_bt_kernel<1024, 1, 112><<<896, 256, 0, stream>>>(L, XT, nullptr, out);
}